// Round 2
// 3439.326 us; speedup vs baseline: 1.1228x; 1.1228x over previous
//
#include <hip/hip_runtime.h>

using u16 = unsigned short;
using u32 = unsigned int;

typedef short bf16x8 __attribute__((ext_vector_type(8)));
typedef float f32x4  __attribute__((ext_vector_type(4)));

__device__ __forceinline__ float bf2f(u16 u) {
    union { u32 u; float f; } v; v.u = ((u32)u) << 16; return v.f;
}
__device__ __forceinline__ u16 f2bf(float f) {
    union { float f; u32 u; } v; v.f = f;
    u32 r = v.u + 0x7FFFu + ((v.u >> 16) & 1u);   // RNE
    return (u16)(r >> 16);
}
__device__ __forceinline__ float fsig(float x)  { return 1.f / (1.f + __expf(-x)); }
__device__ __forceinline__ float ftanh(float x) { return 1.f - 2.f / (__expf(2.f * x) + 1.f); }

__device__ __forceinline__ uint4 pack8(const u16 h[8]) {
    uint4 u;
    u.x = (u32)h[0] | ((u32)h[1] << 16);
    u.y = (u32)h[2] | ((u32)h[3] << 16);
    u.z = (u32)h[4] | ((u32)h[5] << 16);
    u.w = (u32)h[6] | ((u32)h[7] << 16);
    return u;
}
__device__ __forceinline__ bf16x8 cvt8f(const float* p) {   // fp32x8 -> bf16 frag
    bf16x8 r;
    #pragma unroll
    for (int j = 0; j < 8; ++j) r[j] = (short)f2bf(p[j]);
    return r;
}

// Agent-scope (IC coherence point) accessors. RELAXED only: visibility from
// the access itself (bypasses non-coherent L1/L2); ordering from
// __syncthreads' vmcnt(0) drain. Proven in the round-0 passing kernel.
__device__ __forceinline__ u32 aload(const u32* p) {
    return __hip_atomic_load((u32*)p, __ATOMIC_RELAXED, __HIP_MEMORY_SCOPE_AGENT);
}
__device__ __forceinline__ void astore(u32* p, u32 v) {
    __hip_atomic_store(p, v, __ATOMIC_RELAXED, __HIP_MEMORY_SCOPE_AGENT);
}
__device__ __forceinline__ bf16x8 afrag(const u16* base16) { // 16B via 4 coherent dword loads
    union { u32 w[4]; bf16x8 f; } u;
    const u32* p = (const u32*)base16;
    #pragma unroll
    for (int i = 0; i < 4; ++i) u.w[i] = aload(p + i);
    return u.f;
}

// ---------------------------------------------------------------------------
// Phase 1: x1[t][b][n] = feats[b][t][:] . W_ih1[n][:] + b_ih1[n] + b_hh1[n]
// fp32 split-bf16 3-pass (Ah*Bh + Ah*Bl + Al*Bh, error ~2^-17).
// M=32768, N=512, K=1024. 128x128 tile, BK=64. Layout [T, B, 512] (o =
// (t*64+b)*512+n) — byte-for-byte the round-0 passing kernel's f32 path.
// ---------------------------------------------------------------------------
__global__ __launch_bounds__(256) void x1_gemm(
    const float* __restrict__ feats, const float* __restrict__ Wih1,
    const float* __restrict__ bih1, const float* __restrict__ bhh1,
    float* __restrict__ x1p)
{
    __shared__ uint4 a_hi[128 * 8];
    __shared__ uint4 a_lo[128 * 8];
    __shared__ uint4 b_hi[128 * 8];
    __shared__ uint4 b_lo[128 * 8];
    const int tid  = threadIdx.x;
    const int lane = tid & 63, wave = tid >> 6;
    const int m0 = blockIdx.x * 128, n0 = blockIdx.y * 128;
    const int wm = (wave >> 1) * 64, wn = (wave & 1) * 64;
    const int lr = lane & 15, lk = lane >> 4;

    f32x4 acc[4][4] = {};

    for (int kt = 0; kt < 1024; kt += 64) {
        __syncthreads();
        #pragma unroll
        for (int it = 0; it < 4; ++it) {
            int idx = tid + it * 256;            // 0..1023
            int row = idx >> 3, c8 = idx & 7;
            int sw  = (row << 3) | (c8 ^ (row & 7));
            size_t offA = (size_t)(m0 + row) * 1024 + kt + c8 * 8;
            size_t offB = (size_t)(n0 + row) * 1024 + kt + c8 * 8;
            {
                const float* p = feats + offA;
                float4 v0 = *reinterpret_cast<const float4*>(p);
                float4 v1 = *reinterpret_cast<const float4*>(p + 4);
                float av[8] = {v0.x, v0.y, v0.z, v0.w, v1.x, v1.y, v1.z, v1.w};
                u16 h[8], l[8];
                #pragma unroll
                for (int j = 0; j < 8; ++j) {
                    h[j] = f2bf(av[j]);
                    l[j] = f2bf(av[j] - bf2f(h[j]));
                }
                a_hi[sw] = pack8(h);
                a_lo[sw] = pack8(l);
            }
            {
                const float* p = Wih1 + offB;
                float4 v0 = *reinterpret_cast<const float4*>(p);
                float4 v1 = *reinterpret_cast<const float4*>(p + 4);
                float bv[8] = {v0.x, v0.y, v0.z, v0.w, v1.x, v1.y, v1.z, v1.w};
                u16 h[8], l[8];
                #pragma unroll
                for (int j = 0; j < 8; ++j) {
                    h[j] = f2bf(bv[j]);
                    l[j] = f2bf(bv[j] - bf2f(h[j]));
                }
                b_hi[sw] = pack8(h);
                b_lo[sw] = pack8(l);
            }
        }
        __syncthreads();
        for (int s = 0; s < 3; ++s) {        // hi*hi, hi*lo, lo*hi
            const uint4* ab = (s == 2) ? a_lo : a_hi;
            const uint4* bb = (s == 1) ? b_lo : b_hi;
            #pragma unroll
            for (int kc = 0; kc < 2; ++kc) {
                bf16x8 af[4], bfr[4];
                #pragma unroll
                for (int i = 0; i < 4; ++i) {
                    int row = wm + i * 16 + lr;
                    af[i] = *reinterpret_cast<const bf16x8*>(&ab[(row << 3) | ((kc * 4 + lk) ^ (row & 7))]);
                }
                #pragma unroll
                for (int j = 0; j < 4; ++j) {
                    int row = wn + j * 16 + lr;
                    bfr[j] = *reinterpret_cast<const bf16x8*>(&bb[(row << 3) | ((kc * 4 + lk) ^ (row & 7))]);
                }
                #pragma unroll
                for (int i = 0; i < 4; ++i)
                    #pragma unroll
                    for (int j = 0; j < 4; ++j)
                        acc[i][j] = __builtin_amdgcn_mfma_f32_16x16x32_bf16(af[i], bfr[j], acc[i][j], 0, 0, 0);
            }
        }
    }
    // Epilogue: D row=(lane>>4)*4+q, col=lane&15. Store permuted to [T,B,512].
    #pragma unroll
    for (int j = 0; j < 4; ++j) {
        int n = n0 + wn + j * 16 + lr;
        float bias = bih1[n] + bhh1[n];
        #pragma unroll
        for (int i = 0; i < 4; ++i) {
            #pragma unroll
            for (int q = 0; q < 4; ++q) {
                int m = m0 + wm + i * 16 + lk * 4 + q;
                int b = m >> 9, t = m & 511;
                size_t o = ((size_t)(t * 64 + b)) * 512 + n;
                x1p[o] = acc[i][j][q] + bias;
            }
        }
    }
}

// ---------------------------------------------------------------------------
// Phase 2: batch-local recurrence, NO grid barrier. 8 blocks x 512 thr.
//   blocks 0..3  (P1/layer-1): batch rows bg*16..+15, ALL 512 gate cols.
//     W_hh1 in VGPRs (64/thread). h1 ping through a 3-slot IC ring
//     (linear bf16 [16][128] per slot per bg): publish = shfl-pack + u32
//     astore (proven); self-read next step = afrag (proven).
//   blocks 4..7  (P2/layer-2): same batch rows. W_ih2+W_hh2 in VGPRs.
//     h1 consumed from ring via afrag, prefetched 1 step ahead; h2(r-1)
//     re-read from `out` (same-block stores, __syncthreads-ordered,
//     L1-coherent) + f2bf — numerically identical to a bf16 h2 buffer.
// Sync: one __syncthreads/step/block + monotone relaxed agent flags.
//   prodf[bg] = #h1 steps visible; consf[bg] = #h1 steps consumed.
//   Producer overwrites slot r%3 only after consf >= r-2 (consumer done
//   with h1(r-3)); consumer reads h1(r+1) only after prodf >= r+2.
//   3 slots => producer/consumer overlap (2 slots would serialize P->C).
// Numerics identical to the round-0 passing kernel (same rounding, same
// MFMA accumulation order, bf16 h hand-off, fp32 c in registers).
// ---------------------------------------------------------------------------
__global__ __launch_bounds__(512, 2) void lstm_scan3(
    const float* __restrict__ Whh1, const float* __restrict__ Wih2,
    const float* __restrict__ Whh2, const float* __restrict__ bih2,
    const float* __restrict__ bhh2, const float* __restrict__ x1p,
    u16* __restrict__ h1s,      // ring [3][4][2048 u16] = 49152 B
    u32* __restrict__ prodf,    // [4]
    u32* __restrict__ consf,    // [4]
    float* __restrict__ out)
{
    const int tid = threadIdx.x;
    const int wv = tid >> 6, ln = tid & 63;
    const int lr = ln & 15, lk = ln >> 4;
    const int blk = blockIdx.x;
    const bool is1 = (blk < 4);
    const int bg = is1 ? blk : blk - 4;

    u32* prodp = prodf + bg;
    u32* consp = consf + bg;

    if (is1) {
        // ---------------- P1: layer-1 ----------------
        bf16x8 wf[4][4];
        #pragma unroll
        for (int G = 0; G < 4; ++G) {
            int n = G * 128 + wv * 16 + lr;
            #pragma unroll
            for (int kc = 0; kc < 4; ++kc)
                wf[G][kc] = cvt8f(Whh1 + n * 128 + kc * 32 + lk * 8);
        }
        // this thread's 16 x-values per step: batch rows bg*16+lk*4+q, col wv*16+lr
        const int rowoff = (bg * 16 + lk * 4) * 512 + wv * 16 + lr;
        float xn[4][4], xc[4][4];
        #pragma unroll
        for (int G = 0; G < 4; ++G)
            #pragma unroll
            for (int q = 0; q < 4; ++q)
                xn[G][q] = x1p[rowoff + q * 512 + G * 128];      // t = 0
        float c[4] = {0.f, 0.f, 0.f, 0.f};
        u32 consc = 0;

        for (int r = 0; r < 512; ++r) {
            #pragma unroll
            for (int G = 0; G < 4; ++G)
                #pragma unroll
                for (int q = 0; q < 4; ++q) xc[G][q] = xn[G][q];

            bf16x8 a[4];
            if (r == 0) {
                bf16x8 zz = {0, 0, 0, 0, 0, 0, 0, 0};
                #pragma unroll
                for (int kc = 0; kc < 4; ++kc) a[kc] = zz;
            } else {
                const u16* sb = h1s + (size_t)(((r - 1) % 3) * 4 + bg) * 2048;
                #pragma unroll
                for (int kc = 0; kc < 4; ++kc)
                    a[kc] = afrag(sb + lr * 128 + kc * 32 + lk * 8);
            }
            if (r + 1 < 512) {   // next-step x prefetch, off critical path
                const float* xb = x1p + (size_t)(r + 1) * 32768 + rowoff;
                #pragma unroll
                for (int G = 0; G < 4; ++G)
                    #pragma unroll
                    for (int q = 0; q < 4; ++q)
                        xn[G][q] = xb[q * 512 + G * 128];
            }
            f32x4 acc[4] = {};
            #pragma unroll
            for (int kc = 0; kc < 4; ++kc)
                #pragma unroll
                for (int G = 0; G < 4; ++G)
                    acc[G] = __builtin_amdgcn_mfma_f32_16x16x32_bf16(a[kc], wf[G][kc], acc[G], 0, 0, 0);

            if (r >= 3) {   // ring back-pressure: slot r%3 holds h1(r-3)
                u32 need = (u32)(r - 2);
                while (consc < need) {
                    consc = aload(consp);
                    if (consc < need) __builtin_amdgcn_s_sleep(2);
                }
            }
            u32* ob = (u32*)(h1s + (size_t)((r % 3) * 4 + bg) * 2048);
            #pragma unroll
            for (int q = 0; q < 4; ++q) {
                float pi = acc[0][q] + xc[0][q];
                float pf = acc[1][q] + xc[1][q];
                float pg = acc[2][q] + xc[2][q];
                float po = acc[3][q] + xc[3][q];
                float ig = fsig(pi), fg = fsig(pf), gg = ftanh(pg), og = fsig(po);
                c[q] = fg * c[q] + ig * gg;
                float h = og * ftanh(c[q]);
                u32 mine = f2bf(h);
                u32 part = (u32)__shfl_xor((int)mine, 1, 64);
                if (!(lr & 1))
                    astore(ob + (lk * 4 + q) * 64 + ((wv * 16 + lr) >> 1), mine | (part << 16));
            }
            __syncthreads();                        // drains publish vmcnt(0)
            if (tid == 0) astore(prodp, (u32)(r + 1));   // h1(0..r) visible
        }
    } else {
        // ---------------- P2: layer-2 ----------------
        bf16x8 wa[4][4], wb[4][4];
        float b2v[4];
        #pragma unroll
        for (int G = 0; G < 4; ++G) {
            int n = G * 128 + wv * 16 + lr;
            #pragma unroll
            for (int kc = 0; kc < 4; ++kc) {
                wa[G][kc] = cvt8f(Wih2 + n * 128 + kc * 32 + lk * 8);
                wb[G][kc] = cvt8f(Whh2 + n * 128 + kc * 32 + lk * 8);
            }
            b2v[G] = bih2[n] + bhh2[n];
        }
        u32 prodc = 0;
        while (prodc < 1u) {                       // wait h1(0)
            prodc = aload(prodp);
            if (prodc < 1u) __builtin_amdgcn_s_sleep(2);
        }
        bf16x8 a1c[4], a1n[4];
        {
            const u16* sb = h1s + (size_t)bg * 2048;   // slot 0 = h1(0)
            #pragma unroll
            for (int kc = 0; kc < 4; ++kc)
                a1c[kc] = afrag(sb + lr * 128 + kc * 32 + lk * 8);
        }
        const float* selfout = out + (size_t)(bg * 16 + lr) * 512 * 128; // h2 A-frag row = lr
        float c[4] = {0.f, 0.f, 0.f, 0.f};

        for (int r = 0; r < 512; ++r) {
            bf16x8 a2[4];
            if (r == 0) {
                bf16x8 zz = {0, 0, 0, 0, 0, 0, 0, 0};
                #pragma unroll
                for (int kc = 0; kc < 4; ++kc) a2[kc] = zz;
            } else {
                // h2(r-1) from our own out rows (same-CU stores, barrier-ordered)
                const float* hb = selfout + (size_t)(r - 1) * 128;
                #pragma unroll
                for (int kc = 0; kc < 4; ++kc)
                    a2[kc] = cvt8f(hb + kc * 32 + lk * 8);
            }
            f32x4 acc[4] = {};
            #pragma unroll
            for (int kc = 0; kc < 4; ++kc)
                #pragma unroll
                for (int G = 0; G < 4; ++G)
                    acc[G] = __builtin_amdgcn_mfma_f32_16x16x32_bf16(a1c[kc], wa[G][kc], acc[G], 0, 0, 0);
            #pragma unroll
            for (int kc = 0; kc < 4; ++kc)
                #pragma unroll
                for (int G = 0; G < 4; ++G)
                    acc[G] = __builtin_amdgcn_mfma_f32_16x16x32_bf16(a2[kc], wb[G][kc], acc[G], 0, 0, 0);

            if (r + 1 < 512) {   // prefetch h1(r+1) under MFMA drain
                u32 need = (u32)(r + 2);
                while (prodc < need) {
                    prodc = aload(prodp);
                    if (prodc < need) __builtin_amdgcn_s_sleep(2);
                }
                const u16* sb = h1s + (size_t)(((r + 1) % 3) * 4 + bg) * 2048;
                #pragma unroll
                for (int kc = 0; kc < 4; ++kc)
                    a1n[kc] = afrag(sb + lr * 128 + kc * 32 + lk * 8);
            }

            float* orow = out + ((size_t)(bg * 16 + lk * 4) * 512 + r) * 128 + wv * 16 + lr;
            #pragma unroll
            for (int q = 0; q < 4; ++q) {
                float pi = acc[0][q] + b2v[0];
                float pf = acc[1][q] + b2v[1];
                float pg = acc[2][q] + b2v[2];
                float po = acc[3][q] + b2v[3];
                float ig = fsig(pi), fg = fsig(pf), gg = ftanh(pg), og = fsig(po);
                c[q] = fg * c[q] + ig * gg;
                float h = og * ftanh(c[q]);
                orow[(size_t)q * 512 * 128] = h;   // fp32 out; doubles as h2 state
            }
            __syncthreads();                        // out stores drained, L1-visible
            if (tid == 0) astore(consp, (u32)(r + 1));  // ring slot r%3 free
            if (r + 1 < 512) {
                #pragma unroll
                for (int kc = 0; kc < 4; ++kc) a1c[kc] = a1n[kc];
            }
        }
    }
}

// ---------------------------------------------------------------------------
extern "C" void kernel_launch(void* const* d_in, const int* in_sizes, int n_in,
                              void* d_out, int out_size, void* d_ws, size_t ws_size,
                              hipStream_t stream)
{
    const float* feats = (const float*)d_in[0];
    const float* Wih1  = (const float*)d_in[1];
    const float* Whh1  = (const float*)d_in[2];
    const float* bih1  = (const float*)d_in[3];
    const float* bhh1  = (const float*)d_in[4];
    const float* Wih2  = (const float*)d_in[5];
    const float* Whh2  = (const float*)d_in[6];
    const float* bih2  = (const float*)d_in[7];
    const float* bhh2  = (const float*)d_in[8];
    float* out = (float*)d_out;

    const size_t x1b = (size_t)32768 * 512 * 4;    // 64 MB, [T,B,512] f32
    if (ws_size < x1b + 49152 + 128) return;       // <= round-0 requirement; never hit

    char* ws   = (char*)d_ws;
    float* x1p = (float*)ws;
    u16* h1s   = (u16*)(ws + x1b);                 // 3-slot ring, 49152 B
    u32* prodf = (u32*)(ws + x1b + 49152);         // 4 x u32
    u32* consf = (u32*)(ws + x1b + 49152 + 64);    // 4 x u32

    hipMemsetAsync(ws + x1b + 49152, 0, 128, stream);   // zero flags only
    x1_gemm<<<dim3(256, 4), 256, 0, stream>>>(feats, Wih1, bih1, bhh1, x1p);
    lstm_scan3<<<8, 512, 0, stream>>>(Whh1, Wih2, Whh2, bih2, bhh2,
                                      x1p, h1s, prodf, consf, out);
    (void)in_sizes; (void)n_in; (void)out_size;
}

// Round 4
// 2900.826 us; speedup vs baseline: 1.3313x; 1.1856x over previous
//
#include <hip/hip_runtime.h>

using u16 = unsigned short;
using u32 = unsigned int;

typedef short bf16x8 __attribute__((ext_vector_type(8)));
typedef float f32x4  __attribute__((ext_vector_type(4)));

__device__ __forceinline__ float bf2f(u16 u) {
    union { u32 u; float f; } v; v.u = ((u32)u) << 16; return v.f;
}
__device__ __forceinline__ u16 f2bf(float f) {
    union { float f; u32 u; } v; v.f = f;
    u32 r = v.u + 0x7FFFu + ((v.u >> 16) & 1u);   // RNE
    return (u16)(r >> 16);
}
__device__ __forceinline__ float fsig(float x)  { return 1.f / (1.f + __expf(-x)); }
__device__ __forceinline__ float ftanh(float x) { return 1.f - 2.f / (__expf(2.f * x) + 1.f); }

__device__ __forceinline__ uint4 pack8(const u16 h[8]) {
    uint4 u;
    u.x = (u32)h[0] | ((u32)h[1] << 16);
    u.y = (u32)h[2] | ((u32)h[3] << 16);
    u.z = (u32)h[4] | ((u32)h[5] << 16);
    u.w = (u32)h[6] | ((u32)h[7] << 16);
    return u;
}
__device__ __forceinline__ bf16x8 cvt8f(const float* p) {   // fp32x8 -> bf16 frag
    bf16x8 r;
    #pragma unroll
    for (int j = 0; j < 8; ++j) r[j] = (short)f2bf(p[j]);
    return r;
}

__device__ __forceinline__ void gld_lds16(const void* g, void* l) {
    // async global->LDS, 16B/lane; global src is PER-LANE addr, LDS dst is
    // wave-uniform base (+lane*16 added by HW). m97-proven pattern.
    __builtin_amdgcn_global_load_lds(
        (const __attribute__((address_space(1))) unsigned int*)g,
        (__attribute__((address_space(3))) unsigned int*)l, 16, 0, 0);
}

// ---------------------------------------------------------------------------
// Phase 0: one-time W_hh2 fp32 -> bf16 (65536 elems). L2-resident thereafter.
// ---------------------------------------------------------------------------
__global__ __launch_bounds__(512) void wconv(const float* __restrict__ Whh2,
                                             u16* __restrict__ wbg)
{
    int i = blockIdx.x * 512 + threadIdx.x;
    wbg[i] = f2bf(Whh2[i]);
}

// ---------------------------------------------------------------------------
// Phase 1: x1[t][b][n] = feats[b][t][:] . W_ih1[n][:] + b_ih1[n] + b_hh1[n]
// fp32 split-bf16 3-pass (Ah*Bh + Ah*Bl + Al*Bh, error ~2^-17).
// M=32768, N=512, K=1024. 128x128 tile, BK=64. Layout [T, B, 512].
// Byte-for-byte the round-2 passing kernel.
// ---------------------------------------------------------------------------
__global__ __launch_bounds__(256) void x1_gemm(
    const float* __restrict__ feats, const float* __restrict__ Wih1,
    const float* __restrict__ bih1, const float* __restrict__ bhh1,
    float* __restrict__ x1p)
{
    __shared__ uint4 a_hi[128 * 8];
    __shared__ uint4 a_lo[128 * 8];
    __shared__ uint4 b_hi[128 * 8];
    __shared__ uint4 b_lo[128 * 8];
    const int tid  = threadIdx.x;
    const int lane = tid & 63, wave = tid >> 6;
    const int m0 = blockIdx.x * 128, n0 = blockIdx.y * 128;
    const int wm = (wave >> 1) * 64, wn = (wave & 1) * 64;
    const int lr = lane & 15, lk = lane >> 4;

    f32x4 acc[4][4] = {};

    for (int kt = 0; kt < 1024; kt += 64) {
        __syncthreads();
        #pragma unroll
        for (int it = 0; it < 4; ++it) {
            int idx = tid + it * 256;            // 0..1023
            int row = idx >> 3, c8 = idx & 7;
            int sw  = (row << 3) | (c8 ^ (row & 7));
            size_t offA = (size_t)(m0 + row) * 1024 + kt + c8 * 8;
            size_t offB = (size_t)(n0 + row) * 1024 + kt + c8 * 8;
            {
                const float* p = feats + offA;
                float4 v0 = *reinterpret_cast<const float4*>(p);
                float4 v1 = *reinterpret_cast<const float4*>(p + 4);
                float av[8] = {v0.x, v0.y, v0.z, v0.w, v1.x, v1.y, v1.z, v1.w};
                u16 h[8], l[8];
                #pragma unroll
                for (int j = 0; j < 8; ++j) {
                    h[j] = f2bf(av[j]);
                    l[j] = f2bf(av[j] - bf2f(h[j]));
                }
                a_hi[sw] = pack8(h);
                a_lo[sw] = pack8(l);
            }
            {
                const float* p = Wih1 + offB;
                float4 v0 = *reinterpret_cast<const float4*>(p);
                float4 v1 = *reinterpret_cast<const float4*>(p + 4);
                float bv[8] = {v0.x, v0.y, v0.z, v0.w, v1.x, v1.y, v1.z, v1.w};
                u16 h[8], l[8];
                #pragma unroll
                for (int j = 0; j < 8; ++j) {
                    h[j] = f2bf(bv[j]);
                    l[j] = f2bf(bv[j] - bf2f(h[j]));
                }
                b_hi[sw] = pack8(h);
                b_lo[sw] = pack8(l);
            }
        }
        __syncthreads();
        for (int s = 0; s < 3; ++s) {        // hi*hi, hi*lo, lo*hi
            const uint4* ab = (s == 2) ? a_lo : a_hi;
            const uint4* bb = (s == 1) ? b_lo : b_hi;
            #pragma unroll
            for (int kc = 0; kc < 2; ++kc) {
                bf16x8 af[4], bfr[4];
                #pragma unroll
                for (int i = 0; i < 4; ++i) {
                    int row = wm + i * 16 + lr;
                    af[i] = *reinterpret_cast<const bf16x8*>(&ab[(row << 3) | ((kc * 4 + lk) ^ (row & 7))]);
                }
                #pragma unroll
                for (int j = 0; j < 4; ++j) {
                    int row = wn + j * 16 + lr;
                    bfr[j] = *reinterpret_cast<const bf16x8*>(&bb[(row << 3) | ((kc * 4 + lk) ^ (row & 7))]);
                }
                #pragma unroll
                for (int i = 0; i < 4; ++i)
                    #pragma unroll
                    for (int j = 0; j < 4; ++j)
                        acc[i][j] = __builtin_amdgcn_mfma_f32_16x16x32_bf16(af[i], bfr[j], acc[i][j], 0, 0, 0);
            }
        }
    }
    // Epilogue: D row=(lane>>4)*4+q, col=lane&15. Store permuted to [T,B,512].
    #pragma unroll
    for (int j = 0; j < 4; ++j) {
        int n = n0 + wn + j * 16 + lr;
        float bias = bih1[n] + bhh1[n];
        #pragma unroll
        for (int i = 0; i < 4; ++i) {
            #pragma unroll
            for (int q = 0; q < 4; ++q) {
                int m = m0 + wm + i * 16 + lk * 4 + q;
                int b = m >> 9, t = m & 511;
                size_t o = ((size_t)(t * 64 + b)) * 512 + n;
                x1p[o] = acc[i][j][q] + bias;
            }
        }
    }
}

// ---------------------------------------------------------------------------
// Phase 2: FULLY FUSED scan. 4 blocks x 512 thr; block bg owns batch rows
// bg*16..+15 and computes BOTH layers. ZERO cross-block communication ->
// deterministic, replay-safe. Per step r (one __syncthreads):
//   read a1 = h1(r) frags (LDS, swizzled);
//   stage x1(r+2) -> LDS x-buffer (global_load_lds, m97 pattern);
//   acc2 = sum_kc a1*wa  + sum_kc a2*wb   (layer-2 pre-acts)
//   acch = sum_kc a1*wf                    (layer-1(r+1) pre-acts)
//   gates-L2 -> h2(r) (LDS bf16) + out (fp32);
//   gates-L1 (acch + x1(r+1) from LDS) -> h1(r+1) (LDS bf16);
//   barrier.
// Weights: W_hh1,W_ih2 persistent in VGPRs (128/thread); W_hh2 as bf16 in
// L2 (wbg, from wconv), frag-loaded per step. MFMA accumulation order and
// all rounding identical to the round-2 passing kernel.
// Thread mapping (round-2 proven): gate col n = G*128 + wv*16+lr; batch
// row = lk*4+q. C/D layout: row=(lane>>4)*4+q, col=lane&15 matches.
// LDS h tiles [16][128] bf16 swizzled: slot' = (col>>3) ^ (row&15)
// (write) == ((kc*4+lk) ^ lr) (frag read) -- HW-verified round-3 launch 1.
// ---------------------------------------------------------------------------
__global__ __launch_bounds__(512) void lstm_fused(
    const float* __restrict__ Whh1, const float* __restrict__ Wih2,
    const u16*  __restrict__ wbg,   const float* __restrict__ bih2,
    const float* __restrict__ bhh2, const float* __restrict__ x1p,
    float* __restrict__ out)
{
    __shared__ __align__(16) char smem[81920];
    // [0, 65536): x1 tile ping-pong, 2 x [16][512] f32 (x1(t) in buf t&1)
    // [65536, 73728): h1 ping-pong 2 x 4096   (h1(t) in buf t&1)
    // [73728, 81920): h2 ping-pong 2 x 4096   (h2(t) in buf t&1)
    char* xb  = smem;
    char* h1b = smem + 65536;
    char* h2b = smem + 73728;

    const int tid = threadIdx.x;
    const int wv = tid >> 6, ln = tid & 63;
    const int lr = ln & 15, lk = ln >> 4;
    const int bg = blockIdx.x;
    const int colP = wv * 16 + lr;       // hidden col j
    const int rowB = lk * 4;             // batch row base (q adds 0..3)

    // persistent weights: B[k][n]=W[n][k]; lane holds n=(G,wv,lr), k=kc*32+lk*8
    bf16x8 wf[4][4], wa[4][4];
    float b2v[4];
    #pragma unroll
    for (int G = 0; G < 4; ++G) {
        int n = G * 128 + colP;
        #pragma unroll
        for (int kc = 0; kc < 4; ++kc) {
            wf[G][kc] = cvt8f(Whh1 + n * 128 + kc * 32 + lk * 8);
            wa[G][kc] = cvt8f(Wih2 + n * 128 + kc * 32 + lk * 8);
        }
        b2v[G] = bih2[n] + bhh2[n];
    }

    // zero h2 buf[1] (h2(-1), read at r=0)
    for (int i = tid; i < 1024; i += 512) ((u32*)(h2b + 4096))[i] = 0;

    // stage x1(0) -> xbuf[0]
    {
        const float* s = x1p + (size_t)(bg * 16) * 512 + wv * 1024 + ln * 4;
        char* d = xb + wv * 4096;
        #pragma unroll
        for (int i = 0; i < 4; ++i) gld_lds16(s + i * 256, d + i * 1024);
    }
    __syncthreads();   // x1(0) + h2-zero visible

    float c1[4] = {0.f, 0.f, 0.f, 0.f}, c2[4] = {0.f, 0.f, 0.f, 0.f};

    // --- prologue: h1(0) = gates(x1(0)) (acc = 0 exactly) ---
    #pragma unroll
    for (int q = 0; q < 4; ++q) {
        const float* xr = (const float*)(xb + (rowB + q) * 2048);
        float pi = xr[0 * 128 + colP];
        float pf = xr[1 * 128 + colP];
        float pg = xr[2 * 128 + colP];
        float po = xr[3 * 128 + colP];
        float ig = fsig(pi), fg = fsig(pf), gg = ftanh(pg), og = fsig(po);
        c1[q] = fg * c1[q] + ig * gg;
        float h = og * ftanh(c1[q]);
        int row = rowB + q;
        *(u16*)(h1b + row * 256 + ((((colP >> 3) ^ row) & 15) << 4) + (colP & 7) * 2)
            = f2bf(h);
    }
    // stage x1(1) -> xbuf[1]
    {
        const float* s = x1p + (size_t)(64 + bg * 16) * 512 + wv * 1024 + ln * 4;
        char* d = xb + 32768 + wv * 4096;
        #pragma unroll
        for (int i = 0; i < 4; ++i) gld_lds16(s + i * 256, d + i * 1024);
    }
    __syncthreads();   // h1(0) readable; x1(1) staged (vmcnt drained)

    for (int r = 0; r < 512; ++r) {
        const char* h1rd = h1b + ((r & 1) << 12);          // h1(r)
        char*       h1wr = h1b + (((r + 1) & 1) << 12);    // h1(r+1)
        const char* h2rd = h2b + (((r + 1) & 1) << 12);    // h2(r-1)
        char*       h2wr = h2b + ((r & 1) << 12);          // h2(r)
        const char* xrd  = xb  + (((r + 1) & 1) << 15);    // x1(r+1)

        // a1 frags = h1(r)
        bf16x8 a1[4];
        #pragma unroll
        for (int kc = 0; kc < 4; ++kc)
            a1[kc] = *(const bf16x8*)(h1rd + lr * 256 + ((((kc * 4 + lk) ^ lr) & 15) << 4));

        // stage x1(r+2) -> xbuf[r&1] (latency hides under this whole phase)
        if (r + 2 < 512) {
            const float* s = x1p + (size_t)((r + 2) * 64 + bg * 16) * 512 + wv * 1024 + ln * 4;
            char* d = xb + ((r & 1) << 15) + wv * 4096;
            #pragma unroll
            for (int i = 0; i < 4; ++i) gld_lds16(s + i * 256, d + i * 1024);
        }

        f32x4 acc2[4] = {}, acch[4] = {};
        // layer-2: a1*wa then a2*wb (round-2 order)
        #pragma unroll
        for (int kc = 0; kc < 4; ++kc)
            #pragma unroll
            for (int G = 0; G < 4; ++G)
                acc2[G] = __builtin_amdgcn_mfma_f32_16x16x32_bf16(a1[kc], wa[G][kc], acc2[G], 0, 0, 0);
        #pragma unroll
        for (int kc = 0; kc < 4; ++kc) {
            bf16x8 a2 = *(const bf16x8*)(h2rd + lr * 256 + ((((kc * 4 + lk) ^ lr) & 15) << 4));
            #pragma unroll
            for (int G = 0; G < 4; ++G) {
                bf16x8 wbf = *(const bf16x8*)(wbg + (size_t)(G * 128 + colP) * 128 + kc * 32 + lk * 8);
                acc2[G] = __builtin_amdgcn_mfma_f32_16x16x32_bf16(a2, wbf, acc2[G], 0, 0, 0);
            }
        }
        // layer-1(r+1): a1*wf
        #pragma unroll
        for (int kc = 0; kc < 4; ++kc)
            #pragma unroll
            for (int G = 0; G < 4; ++G)
                acch[G] = __builtin_amdgcn_mfma_f32_16x16x32_bf16(a1[kc], wf[G][kc], acch[G], 0, 0, 0);

        // gates L2 -> h2(r) (LDS) + out (fp32)
        float* orow = out + ((size_t)(bg * 16 + rowB) * 512 + r) * 128 + colP;
        #pragma unroll
        for (int q = 0; q < 4; ++q) {
            float pi = acc2[0][q] + b2v[0];
            float pf = acc2[1][q] + b2v[1];
            float pg = acc2[2][q] + b2v[2];
            float po = acc2[3][q] + b2v[3];
            float ig = fsig(pi), fg = fsig(pf), gg = ftanh(pg), og = fsig(po);
            c2[q] = fg * c2[q] + ig * gg;
            float h = og * ftanh(c2[q]);
            int row = rowB + q;
            *(u16*)(h2wr + row * 256 + ((((colP >> 3) ^ row) & 15) << 4) + (colP & 7) * 2)
                = f2bf(h);
            orow[(size_t)q * 512 * 128] = h;
        }
        // gates L1 -> h1(r+1) using x1(r+1) from LDS
        if (r + 1 < 512) {
            #pragma unroll
            for (int q = 0; q < 4; ++q) {
                const float* xr = (const float*)(xrd + (rowB + q) * 2048);
                float pi = acch[0][q] + xr[0 * 128 + colP];
                float pf = acch[1][q] + xr[1 * 128 + colP];
                float pg = acch[2][q] + xr[2 * 128 + colP];
                float po = acch[3][q] + xr[3 * 128 + colP];
                float ig = fsig(pi), fg = fsig(pf), gg = ftanh(pg), og = fsig(po);
                c1[q] = fg * c1[q] + ig * gg;
                float h = og * ftanh(c1[q]);
                int row = rowB + q;
                *(u16*)(h1wr + row * 256 + ((((colP >> 3) ^ row) & 15) << 4) + (colP & 7) * 2)
                    = f2bf(h);
            }
        }
        __syncthreads();   // drains LDS writes + x-stage vmcnt; next step safe
    }
}

// ---------------------------------------------------------------------------
extern "C" void kernel_launch(void* const* d_in, const int* in_sizes, int n_in,
                              void* d_out, int out_size, void* d_ws, size_t ws_size,
                              hipStream_t stream)
{
    const float* feats = (const float*)d_in[0];
    const float* Wih1  = (const float*)d_in[1];
    const float* Whh1  = (const float*)d_in[2];
    const float* bih1  = (const float*)d_in[3];
    const float* bhh1  = (const float*)d_in[4];
    const float* Wih2  = (const float*)d_in[5];
    const float* Whh2  = (const float*)d_in[6];
    const float* bih2  = (const float*)d_in[7];
    const float* bhh2  = (const float*)d_in[8];
    float* out = (float*)d_out;

    const size_t x1b = (size_t)32768 * 512 * 4;    // 64 MB, [T,B,512] f32
    if (ws_size < x1b + 131072) return;            // + W_hh2 bf16 copy

    char* ws   = (char*)d_ws;
    float* x1p = (float*)ws;
    u16*  wbg  = (u16*)(ws + x1b);                 // 128 KB bf16 W_hh2

    wconv<<<128, 512, 0, stream>>>(Whh2, wbg);
    x1_gemm<<<dim3(256, 4), 256, 0, stream>>>(feats, Wih1, bih1, bhh1, x1p);
    lstm_fused<<<4, 512, 0, stream>>>(Whh1, Wih2, wbg, bih2, bhh2, x1p, out);
    (void)in_sizes; (void)n_in; (void)out_size;
}